// Round 7
// baseline (143.281 us; speedup 1.0000x reference)
//
#include <hip/hip_runtime.h>
#include <math.h>

// QIM1D: r = a*exp(-alpha*th)*sin(k*th)*cos(m*th) * |sum_i c_i*exp(i*w_i*th)|,
// minmax-normalized, +0.5, broadcast to (B,1,L). L=2^21, B=4.
//
// R5 lesson: dur_us (112us) is invariant across radically different kernel
// code (R2 precise-trans == R5 native-trans within 0.7us); our kernels never
// appear in top-5 (all <41.5us vs 42us harness fills). The cost is fixed
// overhead, not kernel time. This round: collapse 4 graph nodes -> 3
// (memset + minmax/last-block-reduce + write) to discriminate
// fixed-cost vs structure-cost.
//
// Numerics: step h = 1/(L-1) ~ 4.8e-7 makes all rotation steps small-angle:
// sin(w*h)=w*h, cos(w*h)=1-(w*h)^2/2 exact to f32 -> no setup kernel needed.

#define L_TOT   2097152
#define NT      256
#define NB      2048          // NB*NT*4 == L_TOT exactly
#define EPSF    1e-8f
#define FLT_BIG 3.402823466e38f

// ws float layout: [0..NB) mins | [NB..2NB) maxes | gmin | inv | counter(u32)
#define WS_GOUT  (2*NB)
#define WS_CNT   (2*NB + 2)

// ---------------------------------------------------------------------------
// r for 4 consecutive grid points from j0. Native trans anchors (9 trans) +
// 3 small-angle rotation steps. All parameter loads are wave-uniform
// (scalar-load eligible). ~220 VALU + ~20 trans per thread.
// ---------------------------------------------------------------------------
__device__ __forceinline__ void compute_r4(
    int j0, float a, float alpha, float k, float m,
    const float* __restrict__ delta, const float* __restrict__ E,
    const float* __restrict__ uar, const float* __restrict__ uai,
    const float* __restrict__ ubr, const float* __restrict__ ubi,
    float r[4])
{
    const float h   = 1.0f / (float)(L_TOT - 1);
    const float th0 = (float)j0 * h;

    // normalized coeffs = ub*conj(ua)/((|ua|+eps)(|ub|+eps)); freqs w_i
    float cr[6], ci[6], w[6];
    {
        float na2 = 0.f, nb2 = 0.f;
        float ar[6], ai_[6], br[6], bi_[6];
#pragma unroll
        for (int i = 0; i < 6; ++i) {
            ar[i] = uar[i]; ai_[i] = uai[i]; br[i] = ubr[i]; bi_[i] = ubi[i];
            na2 = fmaf(ar[i], ar[i], fmaf(ai_[i], ai_[i], na2));
            nb2 = fmaf(br[i], br[i], fmaf(bi_[i], bi_[i], nb2));
        }
        const float s = 1.f / ((__fsqrt_rn(na2) + EPSF) * (__fsqrt_rn(nb2) + EPSF));
#pragma unroll
        for (int i = 0; i < 6; ++i) {
            cr[i] = (br[i] * ar[i] + bi_[i] * ai_[i]) * s;
            ci[i] = (bi_[i] * ar[i] - br[i] * ai_[i]) * s;
            w[i]  = -(2.f * E[i] + delta[i]);
        }
    }

    // anchors at th0 (native trans; |args| <= 5 rad, well inside HW range)
    float sk = __sinf(k * th0), ck = __cosf(k * th0);
    float sm = __sinf(m * th0), cm = __cosf(m * th0);
    float e  = a * __expf(-alpha * th0);

    // per-step rotations: small-angle exact in f32
    const float skh = k * h,  ckh = fmaf(-0.5f * skh, skh, 1.0f);
    const float smh = m * h,  cmh = fmaf(-0.5f * smh, smh, 1.0f);
    const float eh  = __expf(-alpha * h);

    float sw[6], cw[6], swh[6], cwh[6];
#pragma unroll
    for (int i = 0; i < 6; ++i) {
        const float ph = w[i] * th0;
        sw[i]  = __sinf(ph);
        cw[i]  = __cosf(ph);
        swh[i] = w[i] * h;
        cwh[i] = fmaf(-0.5f * swh[i], swh[i], 1.0f);
    }

#pragma unroll
    for (int t = 0; t < 4; ++t) {
        float re = 0.f, im = 0.f;
#pragma unroll
        for (int i = 0; i < 6; ++i) {
            re = fmaf(cr[i], cw[i], fmaf(-ci[i], sw[i], re));
            im = fmaf(cr[i], sw[i], fmaf( ci[i], cw[i], im));
        }
        const float S = __fsqrt_rn(fmaf(re, re, im * im));
        r[t] = e * sk * cm * S;

        if (t < 3) {
            e *= eh;
            float ns, nc;
            ns = fmaf(sk, ckh,  ck * skh); nc = fmaf(ck, ckh, -sk * skh); sk = ns; ck = nc;
            ns = fmaf(sm, cmh,  cm * smh); nc = fmaf(cm, cmh, -sm * smh); sm = ns; cm = nc;
#pragma unroll
            for (int i = 0; i < 6; ++i) {
                ns = fmaf(sw[i], cwh[i],  cw[i] * swh[i]);
                nc = fmaf(cw[i], cwh[i], -sw[i] * swh[i]);
                sw[i] = ns; cw[i] = nc;
            }
        }
    }
}

__device__ __forceinline__ void block_minmax(float lmin, float lmax,
                                             float* out_min, float* out_max)
{
#pragma unroll
    for (int off = 32; off > 0; off >>= 1) {
        lmin = fminf(lmin, __shfl_down(lmin, off, 64));
        lmax = fmaxf(lmax, __shfl_down(lmax, off, 64));
    }
    __shared__ float smin[NT / 64], smax[NT / 64];
    const int lane = threadIdx.x & 63, wid = threadIdx.x >> 6;
    if (lane == 0) { smin[wid] = lmin; smax[wid] = lmax; }
    __syncthreads();
    if (threadIdx.x == 0) {
        float mn = smin[0], mx = smax[0];
#pragma unroll
        for (int i = 1; i < NT / 64; ++i) { mn = fminf(mn, smin[i]); mx = fmaxf(mx, smax[i]); }
        *out_min = mn; *out_max = mx;
    }
}

// Pass 1: per-block min/max partials; LAST block (device-scope atomic counter)
// folds all partials -> gout = {gmin, 1/(gmax-gmin+eps)}. rocPRIM-style
// threadFenceReduction pattern: write partials, __threadfence (device release),
// atomicAdd (device-coherent), last block fences then reads.
__global__ __launch_bounds__(NT) void qim_minmax(
    const float* __restrict__ a_p, const float* __restrict__ alpha_p,
    const float* __restrict__ k_p, const float* __restrict__ m_p,
    const float* __restrict__ delta, const float* __restrict__ E,
    const float* __restrict__ uar, const float* __restrict__ uai,
    const float* __restrict__ ubr, const float* __restrict__ ubi,
    float* __restrict__ ws, unsigned int* __restrict__ counter)
{
    const int gid = blockIdx.x * NT + threadIdx.x;
    float r[4];
    compute_r4(gid * 4, *a_p, *alpha_p, *k_p, *m_p,
               delta, E, uar, uai, ubr, ubi, r);
    const float lmin = fminf(fminf(r[0], r[1]), fminf(r[2], r[3]));
    const float lmax = fmaxf(fmaxf(r[0], r[1]), fmaxf(r[2], r[3]));
    float mn, mx;
    block_minmax(lmin, lmax, &mn, &mx);

    __shared__ bool amLast;
    if (threadIdx.x == 0) {
        ws[blockIdx.x]      = mn;
        ws[NB + blockIdx.x] = mx;
        __threadfence();                          // release partials (device)
        const unsigned int prev = atomicAdd(counter, 1u);
        amLast = (prev == NB - 1);
        if (amLast) __threadfence();              // acquire before re-reading
    }
    __syncthreads();

    if (amLast) {
        float fmn = FLT_BIG, fmx = -FLT_BIG;
        for (int i = threadIdx.x; i < NB; i += NT) {
            fmn = fminf(fmn, ws[i]);
            fmx = fmaxf(fmx, ws[NB + i]);
        }
        float gmn, gmx;
        block_minmax(fmn, fmx, &gmn, &gmx);
        if (threadIdx.x == 0) {
            ws[WS_GOUT]     = gmn;
            ws[WS_GOUT + 1] = 1.0f / (gmx - gmn + EPSF);
        }
    }
}

// Pass 2: recompute r, normalize, broadcast-write B copies (float4 stores)
__global__ __launch_bounds__(NT) void qim_write(
    const float* __restrict__ a_p, const float* __restrict__ alpha_p,
    const float* __restrict__ k_p, const float* __restrict__ m_p,
    const float* __restrict__ delta, const float* __restrict__ E,
    const float* __restrict__ uar, const float* __restrict__ uai,
    const float* __restrict__ ubr, const float* __restrict__ ubi,
    const float* __restrict__ ws, float* __restrict__ out, int copies)
{
    const int gid = blockIdx.x * NT + threadIdx.x;
    const int j0  = gid * 4;
    float r[4];
    compute_r4(j0, *a_p, *alpha_p, *k_p, *m_p,
               delta, E, uar, uai, ubr, ubi, r);
    const float gmin = ws[WS_GOUT], inv = ws[WS_GOUT + 1];
    float4 o;
    o.x = fmaf(r[0] - gmin, inv, 0.5f);
    o.y = fmaf(r[1] - gmin, inv, 0.5f);
    o.z = fmaf(r[2] - gmin, inv, 0.5f);
    o.w = fmaf(r[3] - gmin, inv, 0.5f);
    for (int b = 0; b < copies; ++b)
        *reinterpret_cast<float4*>(out + (size_t)b * L_TOT + j0) = o;
}

extern "C" void kernel_launch(void* const* d_in, const int* in_sizes, int n_in,
                              void* d_out, int out_size, void* d_ws, size_t ws_size,
                              hipStream_t stream)
{
    const float* a_p     = (const float*)d_in[0];
    const float* alpha_p = (const float*)d_in[1];
    const float* k_p     = (const float*)d_in[2];
    const float* m_p     = (const float*)d_in[3];
    const float* delta   = (const float*)d_in[4];
    const float* E       = (const float*)d_in[5];
    const float* uar     = (const float*)d_in[6];
    const float* uai     = (const float*)d_in[7];
    const float* ubr     = (const float*)d_in[8];
    const float* ubi     = (const float*)d_in[9];
    float* out = (float*)d_out;
    float* wsf = (float*)d_ws;
    unsigned int* counter = (unsigned int*)(wsf + WS_CNT);

    const int copies = out_size / L_TOT;  // == 4

    // ws is poisoned 0xAA before every timed call -> zero the atomic counter.
    hipMemsetAsync(counter, 0, sizeof(unsigned int), stream);

    qim_minmax<<<NB, NT, 0, stream>>>(a_p, alpha_p, k_p, m_p, delta, E,
                                      uar, uai, ubr, ubi, wsf, counter);
    qim_write<<<NB, NT, 0, stream>>>(a_p, alpha_p, k_p, m_p, delta, E,
                                     uar, uai, ubr, ubi, wsf, out, copies);
}

// Round 10
// 113.411 us; speedup vs baseline: 1.2634x; 1.2634x over previous
//
#include <hip/hip_runtime.h>
#include <math.h>

// QIM1D: r = a*exp(-alpha*th)*sin(k*th)*cos(m*th) * |sum_i c_i*exp(i*w_i*th)|,
// minmax-normalized, +0.5, broadcast to (B,1,L). L=2^21, B=4.
//
// R7 lesson: qim_minmax = 46.5us with VALUBusy 12.6%, ~0 HBM, 0 conflicts ->
// stalled on nothing visible; duration invariant to instruction count
// (R2 precise == R5 native) but proportional to the one constant: 2048 wgs
// (~23ns/wg). R8 experiment: 8x fewer workgroups (256 wg x 256 thr x 32
// elem/thread, grid-chunked), atomics 2048->256. Single-lever change.

#define L_TOT   2097152
#define NT      256
#define NWG     256
#define CHUNKS  8                 // NWG*NT*CHUNKS*4 == L_TOT exactly
#define REGION  (NT * CHUNKS * 4) // 8192 elements per workgroup
#define EPSF    1e-8f
#define FLT_BIG 3.402823466e38f

// ws float layout: [0..NWG) mins | [NWG..2NWG) maxes | gmin,inv | counter
#define WS_GOUT  (2*NWG)
#define WS_CNT   (2*NWG + 2)

struct QimCoef {
    float cr[6], ci[6], w[6];
    float a, alpha, k, m;
};

// Thread-uniform coefficient math (hoisted out of the chunk loop).
__device__ __forceinline__ QimCoef setup_coeffs(
    float a, float alpha, float k, float m,
    const float* __restrict__ delta, const float* __restrict__ E,
    const float* __restrict__ uar, const float* __restrict__ uai,
    const float* __restrict__ ubr, const float* __restrict__ ubi)
{
    QimCoef q;
    float na2 = 0.f, nb2 = 0.f;
    float ar[6], ai_[6], br[6], bi_[6];
#pragma unroll
    for (int i = 0; i < 6; ++i) {
        ar[i] = uar[i]; ai_[i] = uai[i]; br[i] = ubr[i]; bi_[i] = ubi[i];
        na2 = fmaf(ar[i], ar[i], fmaf(ai_[i], ai_[i], na2));
        nb2 = fmaf(br[i], br[i], fmaf(bi_[i], bi_[i], nb2));
    }
    const float s = 1.f / ((__fsqrt_rn(na2) + EPSF) * (__fsqrt_rn(nb2) + EPSF));
#pragma unroll
    for (int i = 0; i < 6; ++i) {
        q.cr[i] = (br[i] * ar[i] + bi_[i] * ai_[i]) * s;
        q.ci[i] = (bi_[i] * ar[i] - br[i] * ai_[i]) * s;
        q.w[i]  = -(2.f * E[i] + delta[i]);
    }
    q.a = a; q.alpha = alpha; q.k = k; q.m = m;
    return q;
}

// r for 4 consecutive grid points from j0: native-trans anchors at th0 +
// 3 small-angle rotation steps (h ~ 4.8e-7 -> sin x = x, cos x = 1 - x^2/2
// exact to f32).
__device__ __forceinline__ void eval4(const QimCoef& q, int j0, float r[4])
{
    const float h   = 1.0f / (float)(L_TOT - 1);
    const float th0 = (float)j0 * h;

    float sk = __sinf(q.k * th0), ck = __cosf(q.k * th0);
    float sm = __sinf(q.m * th0), cm = __cosf(q.m * th0);
    float e  = q.a * __expf(-q.alpha * th0);

    const float skh = q.k * h, ckh = fmaf(-0.5f * skh, skh, 1.0f);
    const float smh = q.m * h, cmh = fmaf(-0.5f * smh, smh, 1.0f);
    const float eh  = __expf(-q.alpha * h);

    float sw[6], cw[6], swh[6], cwh[6];
#pragma unroll
    for (int i = 0; i < 6; ++i) {
        const float ph = q.w[i] * th0;
        sw[i]  = __sinf(ph);
        cw[i]  = __cosf(ph);
        swh[i] = q.w[i] * h;
        cwh[i] = fmaf(-0.5f * swh[i], swh[i], 1.0f);
    }

#pragma unroll
    for (int t = 0; t < 4; ++t) {
        float re = 0.f, im = 0.f;
#pragma unroll
        for (int i = 0; i < 6; ++i) {
            re = fmaf(q.cr[i], cw[i], fmaf(-q.ci[i], sw[i], re));
            im = fmaf(q.cr[i], sw[i], fmaf( q.ci[i], cw[i], im));
        }
        const float S = __fsqrt_rn(fmaf(re, re, im * im));
        r[t] = e * sk * cm * S;

        if (t < 3) {
            e *= eh;
            float ns, nc;
            ns = fmaf(sk, ckh,  ck * skh); nc = fmaf(ck, ckh, -sk * skh); sk = ns; ck = nc;
            ns = fmaf(sm, cmh,  cm * smh); nc = fmaf(cm, cmh, -sm * smh); sm = ns; cm = nc;
#pragma unroll
            for (int i = 0; i < 6; ++i) {
                ns = fmaf(sw[i], cwh[i],  cw[i] * swh[i]);
                nc = fmaf(cw[i], cwh[i], -sw[i] * swh[i]);
                sw[i] = ns; cw[i] = nc;
            }
        }
    }
}

__device__ __forceinline__ void block_minmax(float lmin, float lmax,
                                             float* out_min, float* out_max)
{
#pragma unroll
    for (int off = 32; off > 0; off >>= 1) {
        lmin = fminf(lmin, __shfl_down(lmin, off, 64));
        lmax = fmaxf(lmax, __shfl_down(lmax, off, 64));
    }
    __shared__ float smin[NT / 64], smax[NT / 64];
    const int lane = threadIdx.x & 63, wid = threadIdx.x >> 6;
    if (lane == 0) { smin[wid] = lmin; smax[wid] = lmax; }
    __syncthreads();
    if (threadIdx.x == 0) {
        float mn = smin[0], mx = smax[0];
#pragma unroll
        for (int i = 1; i < NT / 64; ++i) { mn = fminf(mn, smin[i]); mx = fmaxf(mx, smax[i]); }
        *out_min = mn; *out_max = mx;
    }
}

// Pass 1: per-block min/max over REGION elems; last block (device atomic,
// rocPRIM threadFenceReduction pattern) folds NWG pairs -> gmin, inv_range.
__global__ __launch_bounds__(NT) void qim_minmax(
    const float* __restrict__ a_p, const float* __restrict__ alpha_p,
    const float* __restrict__ k_p, const float* __restrict__ m_p,
    const float* __restrict__ delta, const float* __restrict__ E,
    const float* __restrict__ uar, const float* __restrict__ uai,
    const float* __restrict__ ubr, const float* __restrict__ ubi,
    float* __restrict__ ws, unsigned int* __restrict__ counter)
{
    const QimCoef q = setup_coeffs(*a_p, *alpha_p, *k_p, *m_p,
                                   delta, E, uar, uai, ubr, ubi);
    const int base = blockIdx.x * REGION + threadIdx.x * 4;
    float lmin = FLT_BIG, lmax = -FLT_BIG;
#pragma unroll
    for (int c = 0; c < CHUNKS; ++c) {
        float r[4];
        eval4(q, base + c * (NT * 4), r);
        lmin = fminf(lmin, fminf(fminf(r[0], r[1]), fminf(r[2], r[3])));
        lmax = fmaxf(lmax, fmaxf(fmaxf(r[0], r[1]), fmaxf(r[2], r[3])));
    }
    float mn, mx;
    block_minmax(lmin, lmax, &mn, &mx);

    __shared__ bool amLast;
    if (threadIdx.x == 0) {
        ws[blockIdx.x]       = mn;
        ws[NWG + blockIdx.x] = mx;
        __threadfence();                          // release partials (device)
        const unsigned int prev = atomicAdd(counter, 1u);
        amLast = (prev == NWG - 1);
        if (amLast) __threadfence();              // acquire before re-reading
    }
    __syncthreads();

    if (amLast) {
        float fmn = FLT_BIG, fmx = -FLT_BIG;
        for (int i = threadIdx.x; i < NWG; i += NT) {
            fmn = fminf(fmn, ws[i]);
            fmx = fmaxf(fmx, ws[NWG + i]);
        }
        float gmn, gmx;
        block_minmax(fmn, fmx, &gmn, &gmx);
        if (threadIdx.x == 0) {
            ws[WS_GOUT]     = gmn;
            ws[WS_GOUT + 1] = 1.0f / (gmx - gmn + EPSF);
        }
    }
}

// Pass 2: recompute r, normalize, broadcast-write B copies (coalesced float4).
__global__ __launch_bounds__(NT) void qim_write(
    const float* __restrict__ a_p, const float* __restrict__ alpha_p,
    const float* __restrict__ k_p, const float* __restrict__ m_p,
    const float* __restrict__ delta, const float* __restrict__ E,
    const float* __restrict__ uar, const float* __restrict__ uai,
    const float* __restrict__ ubr, const float* __restrict__ ubi,
    const float* __restrict__ ws, float* __restrict__ out, int copies)
{
    const QimCoef q = setup_coeffs(*a_p, *alpha_p, *k_p, *m_p,
                                   delta, E, uar, uai, ubr, ubi);
    const float gmin = ws[WS_GOUT], inv = ws[WS_GOUT + 1];
    const int base = blockIdx.x * REGION + threadIdx.x * 4;
#pragma unroll
    for (int c = 0; c < CHUNKS; ++c) {
        const int j0 = base + c * (NT * 4);
        float r[4];
        eval4(q, j0, r);
        float4 o;
        o.x = fmaf(r[0] - gmin, inv, 0.5f);
        o.y = fmaf(r[1] - gmin, inv, 0.5f);
        o.z = fmaf(r[2] - gmin, inv, 0.5f);
        o.w = fmaf(r[3] - gmin, inv, 0.5f);
        for (int b = 0; b < copies; ++b)
            *reinterpret_cast<float4*>(out + (size_t)b * L_TOT + j0) = o;
    }
}

extern "C" void kernel_launch(void* const* d_in, const int* in_sizes, int n_in,
                              void* d_out, int out_size, void* d_ws, size_t ws_size,
                              hipStream_t stream)
{
    const float* a_p     = (const float*)d_in[0];
    const float* alpha_p = (const float*)d_in[1];
    const float* k_p     = (const float*)d_in[2];
    const float* m_p     = (const float*)d_in[3];
    const float* delta   = (const float*)d_in[4];
    const float* E       = (const float*)d_in[5];
    const float* uar     = (const float*)d_in[6];
    const float* uai     = (const float*)d_in[7];
    const float* ubr     = (const float*)d_in[8];
    const float* ubi     = (const float*)d_in[9];
    float* out = (float*)d_out;
    float* wsf = (float*)d_ws;
    unsigned int* counter = (unsigned int*)(wsf + WS_CNT);

    const int copies = out_size / L_TOT;  // == 4

    // ws is poisoned 0xAA before every timed call -> zero the atomic counter.
    hipMemsetAsync(counter, 0, sizeof(unsigned int), stream);

    qim_minmax<<<NWG, NT, 0, stream>>>(a_p, alpha_p, k_p, m_p, delta, E,
                                       uar, uai, ubr, ubi, wsf, counter);
    qim_write<<<NWG, NT, 0, stream>>>(a_p, alpha_p, k_p, m_p, delta, E,
                                      uar, uai, ubr, ubi, wsf, out, copies);
}